// Round 12
// baseline (382.553 us; speedup 1.0000x reference)
//
#include <hip/hip_runtime.h>
#include <hip/hip_bf16.h>

using u16 = unsigned short;
typedef __attribute__((ext_vector_type(8))) __bf16 bf16x8;
typedef __attribute__((ext_vector_type(4))) float f32x4;
typedef __attribute__((ext_vector_type(16))) float f32x16;
typedef __attribute__((ext_vector_type(4))) unsigned int u32x4;
typedef __attribute__((ext_vector_type(2))) unsigned int u32x2;

#define LN_EPS 1e-5f
#define ATT_SCALE 0.08838834764831845f   // 1/sqrt(128)

__device__ __forceinline__ u16 f2bf(float f) {
    unsigned int u = __builtin_bit_cast(unsigned int, f);
    u += 0x7FFFu + ((u >> 16) & 1u);     // RNE
    return (u16)(u >> 16);
}

__device__ __forceinline__ bf16x8 ld_frag(const u16* p) {
    return __builtin_bit_cast(bf16x8, *(const u32x4*)p);
}

// pack two f32 -> two bf16 (truncate) in one v_perm
__device__ __forceinline__ unsigned pack_bf2(float lo, float hi) {
    return __builtin_amdgcn_perm(__builtin_bit_cast(unsigned, hi),
                                 __builtin_bit_cast(unsigned, lo), 0x07060302u);
}

__device__ __forceinline__ void gl_lds(const u16* g, u16* l) {
    __builtin_amdgcn_global_load_lds((const __attribute__((address_space(1))) void*)g,
                                     (__attribute__((address_space(3))) void*)l, 16, 0, 0);
}

// ---------------------------------------------------------------- fused: weight-convert + LN1
__global__ __launch_bounds__(256)
void cvt_ln(const float* __restrict__ x, const float* __restrict__ g,
            const float* __restrict__ b, u16* __restrict__ hout,
            const float* __restrict__ w_qkv, const float* __restrict__ w_proj,
            const float* __restrict__ w1, const float* __restrict__ w2,
            u16* __restrict__ wout)
{
    const int t = threadIdx.x;
    if (blockIdx.x < 8192) {
        const int row = blockIdx.x;
        const float4 v = ((const float4*)(x + (size_t)row * 1024))[t];
        float s  = v.x + v.y + v.z + v.w;
        float ss = v.x * v.x + v.y * v.y + v.z * v.z + v.w * v.w;
        #pragma unroll
        for (int d = 32; d > 0; d >>= 1) { s += __shfl_down(s, d); ss += __shfl_down(ss, d); }
        __shared__ float red[8];
        const int wave = t >> 6, lane = t & 63;
        if (lane == 0) { red[wave] = s; red[4 + wave] = ss; }
        __syncthreads();
        const float S  = red[0] + red[1] + red[2] + red[3];
        const float SS = red[4] + red[5] + red[6] + red[7];
        const float mu = S * (1.f / 1024.f);
        const float rstd = rsqrtf(SS * (1.f / 1024.f) - mu * mu + LN_EPS);
        const float4 gv = ((const float4*)g)[t];
        const float4 bv = ((const float4*)b)[t];
        ushort4 ov;
        ov.x = f2bf((v.x - mu) * rstd * gv.x + bv.x);
        ov.y = f2bf((v.y - mu) * rstd * gv.y + bv.y);
        ov.z = f2bf((v.z - mu) * rstd * gv.z + bv.z);
        ov.w = f2bf((v.w - mu) * rstd * gv.w + bv.w);
        ((ushort4*)(hout + (size_t)row * 1024))[t] = ov;
    } else {
        const int i = (blockIdx.x - 8192) * 256 + t;
        const int n_qkv = 3072 * 1024 / 4, n_c = 1024 * 1024 / 4;
        const float* src;
        int j = i;
        if (j < n_qkv) { src = w_qkv; }
        else if ((j -= n_qkv) < n_c) { src = w_proj; }
        else if ((j -= n_c) < n_c)   { src = w1; }
        else { j -= n_c; src = w2; }
        const float4 v = ((const float4*)src)[j];
        ushort4 o;
        o.x = f2bf(v.x); o.y = f2bf(v.y); o.z = f2bf(v.z); o.w = f2bf(v.w);
        ((ushort4*)wout)[i] = o;
    }
}

// ---------------------------------------------------------------- layernorm
__global__ __launch_bounds__(256)
void ln_kernel(const float* __restrict__ x, const float* __restrict__ g,
               const float* __restrict__ b, u16* __restrict__ out)
{
    const int row = blockIdx.x;
    const int t = threadIdx.x;
    const float4 v = ((const float4*)(x + (size_t)row * 1024))[t];
    float s  = v.x + v.y + v.z + v.w;
    float ss = v.x * v.x + v.y * v.y + v.z * v.z + v.w * v.w;
    #pragma unroll
    for (int d = 32; d > 0; d >>= 1) { s += __shfl_down(s, d); ss += __shfl_down(ss, d); }
    __shared__ float red[8];
    const int wave = t >> 6, lane = t & 63;
    if (lane == 0) { red[wave] = s; red[4 + wave] = ss; }
    __syncthreads();
    const float S  = red[0] + red[1] + red[2] + red[3];
    const float SS = red[4] + red[5] + red[6] + red[7];
    const float mu = S * (1.f / 1024.f);
    const float rstd = rsqrtf(SS * (1.f / 1024.f) - mu * mu + LN_EPS);
    const float4 gv = ((const float4*)g)[t];
    const float4 bv = ((const float4*)b)[t];
    ushort4 ov;
    ov.x = f2bf((v.x - mu) * rstd * gv.x + bv.x);
    ov.y = f2bf((v.y - mu) * rstd * gv.y + bv.y);
    ov.z = f2bf((v.z - mu) * rstd * gv.z + bv.z);
    ov.w = f2bf((v.w - mu) * rstd * gv.w + bv.w);
    ((ushort4*)(out + (size_t)row * 1024))[t] = ov;
}

// ---------------------------------------------------------------- 128x128 GEMM, BK=32, 4-buffer depth-3
// T4: counted vmcnt (never 0 in-loop) -- stage(t+3) issued each iter; loads stay in flight across
// raw s_barriers so HBM latency (~900cy) spans 3 compute phases. 64KB LDS static -> 2 blocks/CU.
// WAR: barrier #1 confirms all waves done reading buf[(t+3)&3]=buf[(t-1)&3] before overwrite issue.
// RAW: per-thread vmcnt + barrier #2 => buf[t&3] globally populated.
// Swizzle (4 chunks/row): slot s holds global chunk s ^ ((row>>1)&3) -> 16 rows hit 8 b128 bank-sets
// 2x each = conflict-free (2-way is free, m136).
#define WAITVM12 { asm volatile("s_waitcnt vmcnt(12)" ::: "memory"); __builtin_amdgcn_sched_barrier(0); }
#define WAITVM8  { asm volatile("s_waitcnt vmcnt(8)"  ::: "memory"); __builtin_amdgcn_sched_barrier(0); }
#define WAITVM4  { asm volatile("s_waitcnt vmcnt(4)"  ::: "memory"); __builtin_amdgcn_sched_barrier(0); }
#define WAITVM0  { asm volatile("s_waitcnt vmcnt(0)"  ::: "memory"); __builtin_amdgcn_sched_barrier(0); }

#define GEMM_PREAMBLE(Aptr, Bptr, Kdim)                                           \
    __shared__ __align__(16) u16 As[4][128 * 32];                                 \
    __shared__ __align__(16) u16 Bs[4][128 * 32];                                 \
    const int tid  = threadIdx.x;                                                 \
    const int wave = tid >> 6;                                                    \
    const int lane = tid & 63;                                                    \
    const int quad = lane >> 4;                                                   \
    const int l16  = lane & 15;                                                   \
    const int m0 = blockIdx.x * 128;                                              \
    const int n0 = blockIdx.y * 128;                                              \
    const int wm = (wave & 1) * 64;                                               \
    const int wn = (wave >> 1) * 64;                                              \
    f32x4 acc[4][4];                                                              \
    _Pragma("unroll")                                                             \
    for (int i = 0; i < 4; i++)                                                   \
        _Pragma("unroll")                                                         \
        for (int j = 0; j < 4; j++)                                               \
            acc[i][j] = f32x4{0.f, 0.f, 0.f, 0.f};                                \
    /* staging: 2 rounds x 64 rows; thread -> row=rnd*64+(tid>>2), slot=tid&3,   */\
    /* pre-swizzled global chunk = (tid&3) ^ ((tid>>3)&3)                        */\
    const u16* gA = Aptr + (size_t)(m0 + (tid >> 2)) * Kdim                       \
                    + (((tid & 3) ^ ((tid >> 3) & 3)) * 8);                       \
    const u16* gB = Bptr + (size_t)(n0 + (tid >> 2)) * Kdim                       \
                    + (((tid & 3) ^ ((tid >> 3) & 3)) * 8);                       \
    auto STAGE = [&](int kt, int bf) {                                            \
        _Pragma("unroll")                                                         \
        for (int rnd = 0; rnd < 2; rnd++) {                                       \
            gl_lds(gA + (size_t)rnd * 64 * Kdim + kt * 32,                        \
                   &As[bf][rnd * 2048 + wave * 512]);                             \
            gl_lds(gB + (size_t)rnd * 64 * Kdim + kt * 32,                        \
                   &Bs[bf][rnd * 2048 + wave * 512]);                             \
        }                                                                         \
    };                                                                            \
    const int NT = Kdim / 32;                                                     \
    STAGE(0, 0); STAGE(1, 1); STAGE(2, 2);                                        \
    for (int t = 0; t < NT; t++) {                                                \
        __builtin_amdgcn_sched_barrier(0);                                        \
        __builtin_amdgcn_s_barrier();   /* #1: reads of buf[(t-1)&3] done */      \
        __builtin_amdgcn_sched_barrier(0);                                        \
        if (t + 3 < NT) STAGE(t + 3, (t + 3) & 3);                                \
        if (t < NT - 3)       WAITVM12                                            \
        else if (t == NT - 3) WAITVM8                                             \
        else if (t == NT - 2) WAITVM4                                             \
        else                  WAITVM0                                             \
        __builtin_amdgcn_s_barrier();   /* #2: buf[t&3] globally populated */     \
        __builtin_amdgcn_sched_barrier(0);                                        \
        const u16* curA = As[t & 3];                                              \
        const u16* curB = Bs[t & 3];                                              \
        bf16x8 af[4], bfv[4];                                                     \
        _Pragma("unroll")                                                         \
        for (int i = 0; i < 4; i++) {                                             \
            const int row = wm + i * 16 + l16;                                    \
            const int c = quad ^ ((row >> 1) & 3);                                \
            af[i] = ld_frag(&curA[row * 32 + c * 8]);                             \
        }                                                                         \
        _Pragma("unroll")                                                         \
        for (int j = 0; j < 4; j++) {                                             \
            const int row = wn + j * 16 + l16;                                    \
            const int c = quad ^ ((row >> 1) & 3);                                \
            bfv[j] = ld_frag(&curB[row * 32 + c * 8]);                            \
        }                                                                         \
        __builtin_amdgcn_s_setprio(1);                                            \
        _Pragma("unroll")                                                         \
        for (int i = 0; i < 4; i++)                                               \
            _Pragma("unroll")                                                     \
            for (int j = 0; j < 4; j++)                                           \
                acc[i][j] = __builtin_amdgcn_mfma_f32_16x16x32_bf16(              \
                    af[i], bfv[j], acc[i][j], 0, 0, 0);                           \
        __builtin_amdgcn_s_setprio(0);                                            \
    }

// qkv: Q (scaled) and K -> Cb[tok][2048]; V -> Cv transposed [bh][d][tok]  (R2 scatter epilogue)
__global__ __launch_bounds__(256, 2)
void gemm_qkv(const u16* __restrict__ A, const u16* __restrict__ Bw,
              u16* __restrict__ Cb, u16* __restrict__ Cv)
{
    GEMM_PREAMBLE(A, Bw, 1024)

    #pragma unroll
    for (int j = 0; j < 4; j++) {
        const int gn = n0 + wn + j * 16 + l16;
        if (gn < 2048) {
            const float qs = (gn < 1024) ? ATT_SCALE : 1.0f;
            #pragma unroll
            for (int i = 0; i < 4; i++) {
                const int gm0 = m0 + wm + i * 16 + quad * 4;
                #pragma unroll
                for (int r = 0; r < 4; r++)
                    Cb[(size_t)(gm0 + r) * 2048 + gn] = f2bf(acc[i][j][r] * qs);
            }
        } else {
            const int hh = (gn >> 7) & 7, dd = gn & 127;
            #pragma unroll
            for (int i = 0; i < 4; i++) {
                const int gm0 = m0 + wm + i * 16 + quad * 4;
                #pragma unroll
                for (int r = 0; r < 4; r++) {
                    const int tok = gm0 + r;
                    Cv[((size_t)((tok >> 11) * 8 + hh) * 128 + dd) * 2048 + (tok & 2047)] =
                        f2bf(acc[i][j][r]);
                }
            }
        }
    }
}

// C-sized matmuls: EPI 1 +bias+res f32; EPI 2 +bias ELU bf16; EPI 3 +bias ELU BN +res f32
template <int EPI>
__global__ __launch_bounds__(256, 2)
void gemm_c(const u16* __restrict__ A, const u16* __restrict__ Bw,
            const float* __restrict__ bias, const float* __restrict__ res,
            float* __restrict__ Cf, u16* __restrict__ Cb,
            const float* __restrict__ bng, const float* __restrict__ bnb,
            const float* __restrict__ bnm, const float* __restrict__ bnv)
{
    const int N = 1024;
    GEMM_PREAMBLE(A, Bw, 1024)

    #pragma unroll
    for (int j = 0; j < 4; j++) {
        const int gn = n0 + wn + j * 16 + l16;
        float bs = bias[gn], sc = 0.f, sh = 0.f;
        if constexpr (EPI == 3) {
            const float iv = rsqrtf(bnv[gn] + LN_EPS);
            sc = bng[gn] * iv;
            sh = bnb[gn] - bnm[gn] * sc;
        }
        #pragma unroll
        for (int i = 0; i < 4; i++) {
            const int gm0 = m0 + wm + i * 16 + quad * 4;
            #pragma unroll
            for (int r = 0; r < 4; r++) {
                const size_t idx = (size_t)(gm0 + r) * N + gn;
                const float v = acc[i][j][r];
                if constexpr (EPI == 1) {
                    Cf[idx] = res[idx] + v + bs;
                } else if constexpr (EPI == 2) {
                    float t = v + bs;
                    t = t > 0.f ? t : (__expf(t) - 1.f);
                    Cb[idx] = f2bf(t);
                } else {
                    float t = v + bs;
                    t = t > 0.f ? t : (__expf(t) - 1.f);
                    t = t * sc + sh;
                    Cf[idx] = res[idx] + t;
                }
            }
        }
    }
}

// ---------------------------------------------------------------- flash attention (R8 version: proven 84.3us)
// grid 512 (XCD-swizzled), 256 thr = 4 waves; 128 q/block; K-tile 64; D=128; K+V dbuf in LDS; 2 blocks/CU
// T5 setprio around MFMA; P^T half-swap via v_permlane32_swap (VALU pipe). Lane closed (R3/R5/R9/R10).
__global__ __launch_bounds__(256, 2)
void attn_kernel(const u16* __restrict__ qk, const u16* __restrict__ vT, u16* __restrict__ o)
{
    __shared__ __align__(16) u16 smem[32768];   // 64KB: buf0 [0,16384) buf1 [16384,32768)

    const int tid  = threadIdx.x;
    const int wave = tid >> 6;
    const int lane = tid & 63;
    const int l32  = lane & 31;
    const int hl   = lane >> 5;
    const int id   = blockIdx.x;
    const int bh   = ((id >> 7) << 3) | (id & 7);   // same-bh blocks cluster per XCD
    const int qt   = (id >> 3) & 15;
    const int b    = bh >> 3, h = bh & 7;
    const size_t tok0 = (size_t)b * 2048;

    const u16* qptr = qk + h * 128;
    const u16* kptr = qk + 1024 + h * 128;
    const u16* vptr = vT + (size_t)bh * 128 * 2048;

    // ---- stage Q tile [128 q][128 d] into buf1 region, xor-swizzled rows
    #pragma unroll
    for (int qq = 0; qq < 8; qq++) {
        const int s = qq * 256 + tid;
        const int r = s >> 4;
        const int cg = (s & 15) ^ (r & 7);
        const u16* g = qptr + (tok0 + qt * 128 + r) * 2048 + cg * 8;
        const int sb = 16384 + (qq * 256 + (tid & 192)) * 8;
        gl_lds(g, smem + sb);
    }
    __syncthreads();

    // ---- Q B-fragments (B[k=d][n=q]): n = l32, k = 16*ks + 8*hl + j
    bf16x8 qf[8];
    {
        const int row = wave * 32 + l32;
        #pragma unroll
        for (int ks = 0; ks < 8; ks++) {
            const int c = (ks * 2 + hl) ^ (row & 7);
            qf[ks] = ld_frag(smem + 16384 + row * 128 + c * 8);
        }
    }

    f32x16 oacc[4];
    #pragma unroll
    for (int i = 0; i < 4; i++)
        #pragma unroll
        for (int e = 0; e < 16; e++) oacc[i][e] = 0.f;
    float l_acc = 0.f;

    // ---- prefetch kt=0 into buf0
    {
        #pragma unroll
        for (int qq = 0; qq < 4; qq++) {
            const int s = qq * 256 + tid;
            const int rk = s >> 4, ck = (s & 15) ^ (rk & 7);
            gl_lds(kptr + (tok0 + rk) * 2048 + ck * 8,
                   smem + (qq * 256 + (tid & 192)) * 8);
            const int rv = s >> 3, cv = (s & 7) ^ (rv & 7);
            gl_lds(vptr + (size_t)rv * 2048 + cv * 8,
                   smem + 8192 + (qq * 256 + (tid & 192)) * 8);
        }
    }

    for (int kt = 0; kt < 32; kt++) {
        __syncthreads();

        if (kt + 1 < 32) {
            u16* nb = smem + ((kt + 1) & 1) * 16384;
            #pragma unroll
            for (int qq = 0; qq < 4; qq++) {
                const int s = qq * 256 + tid;
                const int rk = s >> 4, ck = (s & 15) ^ (rk & 7);
                gl_lds(kptr + (tok0 + (kt + 1) * 64 + rk) * 2048 + ck * 8,
                       nb + (qq * 256 + (tid & 192)) * 8);
                const int rv = s >> 3, cv = (s & 7) ^ (rv & 7);
                gl_lds(vptr + (size_t)rv * 2048 + (kt + 1) * 64 + cv * 8,
                       nb + 8192 + (qq * 256 + (tid & 192)) * 8);
            }
        }

        const u16* Ks = smem + (kt & 1) * 16384;
        const u16* Vs = Ks + 8192;

        // ---- S^T = K . Q^T
        f32x16 sacc[2];
        #pragma unroll
        for (int t = 0; t < 2; t++)
            #pragma unroll
            for (int e = 0; e < 16; e++) sacc[t][e] = 0.f;
        __builtin_amdgcn_s_setprio(1);
        #pragma unroll
        for (int ks = 0; ks < 8; ks++) {
            #pragma unroll
            for (int mt = 0; mt < 2; mt++) {
                const int row = mt * 32 + l32;
                const int c = (ks * 2 + hl) ^ (row & 7);
                const bf16x8 kf = ld_frag(Ks + row * 128 + c * 8);
                sacc[mt] = __builtin_amdgcn_mfma_f32_32x32x16_bf16(kf, qf[ks], sacc[mt], 0, 0, 0);
            }
        }
        __builtin_amdgcn_s_setprio(0);

        // ---- p = exp(s), l accumulate, pack bf16
        unsigned pk[2][8];
        #pragma unroll
        for (int t = 0; t < 2; t++) {
            #pragma unroll
            for (int r2 = 0; r2 < 8; r2++) {
                const float p0 = __expf(sacc[t][2 * r2]);
                const float p1 = __expf(sacc[t][2 * r2 + 1]);
                l_acc += p0 + p1;
                pk[t][r2] = pack_bf2(p0, p1);
            }
        }

        // ---- O^T += V^T . P^T : P^T B-frag via permlane32_swap (VALU pipe, no LDS)
        #pragma unroll
        for (int ks = 0; ks < 4; ks++) {
            const int t = ks >> 1;
            const int pb = (ks & 1) * 4;
            const u32x2 r02 = __builtin_amdgcn_permlane32_swap(pk[t][pb + 0], pk[t][pb + 2], false, false);
            const u32x2 r13 = __builtin_amdgcn_permlane32_swap(pk[t][pb + 1], pk[t][pb + 3], false, false);
            u32x4 pu;
            pu.x = r02.x; pu.y = r13.x; pu.z = r02.y; pu.w = r13.y;
            const bf16x8 pf = __builtin_bit_cast(bf16x8, pu);
            __builtin_amdgcn_s_setprio(1);
            #pragma unroll
            for (int dt = 0; dt < 4; dt++) {
                const int row = dt * 32 + l32;
                const int c = (ks * 2 + hl) ^ (row & 7);
                const bf16x8 vf = ld_frag(Vs + row * 64 + c * 8);
                oacc[dt] = __builtin_amdgcn_mfma_f32_32x32x16_bf16(vf, pf, oacc[dt], 0, 0, 0);
            }
            __builtin_amdgcn_s_setprio(0);
        }
    }

    // ---- epilogue: O^T/l -> bf16, transpose via LDS, coalesced store
    __syncthreads();
    u16* Ot = smem;   // [128 q][136]
    const float lt  = l_acc + __shfl_xor(l_acc, 32);
    const float inv = 1.0f / lt;
    const int qloc = wave * 32 + l32;
    #pragma unroll
    for (int dt = 0; dt < 4; dt++) {
        #pragma unroll
        for (int r2 = 0; r2 < 8; r2++) {
            const float v0 = oacc[dt][2 * r2] * inv;
            const float v1 = oacc[dt][2 * r2 + 1] * inv;
            const int dp = dt * 32 + 4 * hl + 2 * (r2 & 1) + 8 * (r2 >> 1);
            *(unsigned*)(Ot + qloc * 136 + dp) = pack_bf2(v0, v1);
        }
    }
    __syncthreads();
    const int qr = tid >> 1;
    const int hh = tid & 1;
    const u16* src = Ot + qr * 136 + hh * 64;
    u16* dst = o + (tok0 + qt * 128 + qr) * 1024 + h * 128 + hh * 64;
    #pragma unroll
    for (int c = 0; c < 8; c++)
        *(u32x4*)(dst + c * 8) = *(const u32x4*)(src + c * 8);
}

// ---------------------------------------------------------------- launch
extern "C" void kernel_launch(void* const* d_in, const int* in_sizes, int n_in,
                              void* d_out, int out_size, void* d_ws, size_t ws_size,
                              hipStream_t stream)
{
    const float* x      = (const float*)d_in[0];
    const float* ln1_g  = (const float*)d_in[1];
    const float* ln1_b  = (const float*)d_in[2];
    const float* w_qkv  = (const float*)d_in[3];
    const float* w_proj = (const float*)d_in[4];
    const float* b_proj = (const float*)d_in[5];
    const float* ln2_g  = (const float*)d_in[6];
    const float* ln2_b  = (const float*)d_in[7];
    const float* w1     = (const float*)d_in[8];
    const float* b1     = (const float*)d_in[9];
    const float* w2     = (const float*)d_in[10];
    const float* b2     = (const float*)d_in[11];
    const float* bn_g   = (const float*)d_in[12];
    const float* bn_b   = (const float*)d_in[13];
    const float* bn_m   = (const float*)d_in[14];
    const float* bn_v   = (const float*)d_in[15];
    float* out = (float*)d_out;

    // workspace carve-up (u16 units), ~124 MB total
    u16* wq   = (u16*)d_ws;                          // 3072*1024
    u16* wp   = wq  + (size_t)3072 * 1024;           // 1024*1024
    u16* w1b  = wp  + (size_t)1024 * 1024;
    u16* w2b  = w1b + (size_t)1024 * 1024;
    u16* hbuf = w2b + (size_t)1024 * 1024;           // 8192*1024 (LN out, reused)
    u16* qkb  = hbuf + (size_t)8192 * 1024;          // 8192*2048 (Q scaled | K)
    u16* vTb  = qkb + (size_t)8192 * 2048;           // 32*128*2048 (V transposed)
    u16* obuf = vTb + (size_t)8192 * 1024;           // 8192*1024 (attn out; reused mlp1 out)
    float* x1 = (float*)(obuf + (size_t)8192 * 1024); // 8192*1024 f32

    cvt_ln<<<14336, 256, 0, stream>>>(x, ln1_g, ln1_b, hbuf, w_qkv, w_proj, w1, w2, wq);

    gemm_qkv<<<dim3(64, 24), 256, 0, stream>>>(hbuf, wq, qkb, vTb);

    attn_kernel<<<512, 256, 0, stream>>>(qkb, vTb, obuf);

    gemm_c<1><<<dim3(64, 8), 256, 0, stream>>>(obuf, wp,
        b_proj, x, x1, nullptr, nullptr, nullptr, nullptr, nullptr);

    ln_kernel<<<8192, 256, 0, stream>>>(x1, ln2_g, ln2_b, hbuf);

    gemm_c<2><<<dim3(64, 8), 256, 0, stream>>>(hbuf, w1b,
        b1, nullptr, nullptr, obuf, nullptr, nullptr, nullptr, nullptr);

    gemm_c<3><<<dim3(64, 8), 256, 0, stream>>>(obuf, w2b,
        b2, x1, out, nullptr, bn_g, bn_b, bn_m, bn_v);
}

// Round 13
// 366.831 us; speedup vs baseline: 1.0429x; 1.0429x over previous
//
#include <hip/hip_runtime.h>
#include <hip/hip_bf16.h>

using u16 = unsigned short;
typedef __attribute__((ext_vector_type(8))) __bf16 bf16x8;
typedef __attribute__((ext_vector_type(4))) float f32x4;
typedef __attribute__((ext_vector_type(16))) float f32x16;
typedef __attribute__((ext_vector_type(4))) unsigned int u32x4;
typedef __attribute__((ext_vector_type(2))) unsigned int u32x2;

#define LN_EPS 1e-5f
#define ATT_SCALE 0.08838834764831845f   // 1/sqrt(128)

__device__ __forceinline__ u16 f2bf(float f) {
    unsigned int u = __builtin_bit_cast(unsigned int, f);
    u += 0x7FFFu + ((u >> 16) & 1u);     // RNE
    return (u16)(u >> 16);
}

__device__ __forceinline__ bf16x8 ld_frag(const u16* p) {
    return __builtin_bit_cast(bf16x8, *(const u32x4*)p);
}

// pack two f32 -> two bf16 (truncate) in one v_perm
__device__ __forceinline__ unsigned pack_bf2(float lo, float hi) {
    return __builtin_amdgcn_perm(__builtin_bit_cast(unsigned, hi),
                                 __builtin_bit_cast(unsigned, lo), 0x07060302u);
}

__device__ __forceinline__ void gl_lds(const u16* g, u16* l) {
    __builtin_amdgcn_global_load_lds((const __attribute__((address_space(1))) void*)g,
                                     (__attribute__((address_space(3))) void*)l, 16, 0, 0);
}

// ---------------------------------------------------------------- fused: weight-convert + LN1
__global__ __launch_bounds__(256)
void cvt_ln(const float* __restrict__ x, const float* __restrict__ g,
            const float* __restrict__ b, u16* __restrict__ hout,
            const float* __restrict__ w_qkv, const float* __restrict__ w_proj,
            const float* __restrict__ w1, const float* __restrict__ w2,
            u16* __restrict__ wout)
{
    const int t = threadIdx.x;
    if (blockIdx.x < 8192) {
        const int row = blockIdx.x;
        const float4 v = ((const float4*)(x + (size_t)row * 1024))[t];
        float s  = v.x + v.y + v.z + v.w;
        float ss = v.x * v.x + v.y * v.y + v.z * v.z + v.w * v.w;
        #pragma unroll
        for (int d = 32; d > 0; d >>= 1) { s += __shfl_down(s, d); ss += __shfl_down(ss, d); }
        __shared__ float red[8];
        const int wave = t >> 6, lane = t & 63;
        if (lane == 0) { red[wave] = s; red[4 + wave] = ss; }
        __syncthreads();
        const float S  = red[0] + red[1] + red[2] + red[3];
        const float SS = red[4] + red[5] + red[6] + red[7];
        const float mu = S * (1.f / 1024.f);
        const float rstd = rsqrtf(SS * (1.f / 1024.f) - mu * mu + LN_EPS);
        const float4 gv = ((const float4*)g)[t];
        const float4 bv = ((const float4*)b)[t];
        ushort4 ov;
        ov.x = f2bf((v.x - mu) * rstd * gv.x + bv.x);
        ov.y = f2bf((v.y - mu) * rstd * gv.y + bv.y);
        ov.z = f2bf((v.z - mu) * rstd * gv.z + bv.z);
        ov.w = f2bf((v.w - mu) * rstd * gv.w + bv.w);
        ((ushort4*)(hout + (size_t)row * 1024))[t] = ov;
    } else {
        const int i = (blockIdx.x - 8192) * 256 + t;
        const int n_qkv = 3072 * 1024 / 4, n_c = 1024 * 1024 / 4;
        const float* src;
        int j = i;
        if (j < n_qkv) { src = w_qkv; }
        else if ((j -= n_qkv) < n_c) { src = w_proj; }
        else if ((j -= n_c) < n_c)   { src = w1; }
        else { j -= n_c; src = w2; }
        const float4 v = ((const float4*)src)[j];
        ushort4 o;
        o.x = f2bf(v.x); o.y = f2bf(v.y); o.z = f2bf(v.z); o.w = f2bf(v.w);
        ((ushort4*)wout)[i] = o;
    }
}

// ---------------------------------------------------------------- layernorm
__global__ __launch_bounds__(256)
void ln_kernel(const float* __restrict__ x, const float* __restrict__ g,
               const float* __restrict__ b, u16* __restrict__ out)
{
    const int row = blockIdx.x;
    const int t = threadIdx.x;
    const float4 v = ((const float4*)(x + (size_t)row * 1024))[t];
    float s  = v.x + v.y + v.z + v.w;
    float ss = v.x * v.x + v.y * v.y + v.z * v.z + v.w * v.w;
    #pragma unroll
    for (int d = 32; d > 0; d >>= 1) { s += __shfl_down(s, d); ss += __shfl_down(ss, d); }
    __shared__ float red[8];
    const int wave = t >> 6, lane = t & 63;
    if (lane == 0) { red[wave] = s; red[4 + wave] = ss; }
    __syncthreads();
    const float S  = red[0] + red[1] + red[2] + red[3];
    const float SS = red[4] + red[5] + red[6] + red[7];
    const float mu = S * (1.f / 1024.f);
    const float rstd = rsqrtf(SS * (1.f / 1024.f) - mu * mu + LN_EPS);
    const float4 gv = ((const float4*)g)[t];
    const float4 bv = ((const float4*)b)[t];
    ushort4 ov;
    ov.x = f2bf((v.x - mu) * rstd * gv.x + bv.x);
    ov.y = f2bf((v.y - mu) * rstd * gv.y + bv.y);
    ov.z = f2bf((v.z - mu) * rstd * gv.z + bv.z);
    ov.w = f2bf((v.w - mu) * rstd * gv.w + bv.w);
    ((ushort4*)(out + (size_t)row * 1024))[t] = ov;
}

// ---------------------------------------------------------------- 128x128 GEMM, BK=64, double-buffered
// R11 loop structure (2-phase dbuf, proven best; R12's counted-vmcnt regressed per m141 mechanism).
// MFMA shape 32x32x16 (m119: 2495 vs 2176 TF; 16 MFMAs/K-step vs 32, same LDS traffic).
// Mappings HW-verified in-file by attn_kernel: A lane->(row=l&31, k=(l>>5)*8+j); B mirror;
// C/D: col=lane&31, row=(r&3)+8*(r>>2)+4*(l>>5).
#define GEMM_PREAMBLE(Aptr, Bptr, Kdim)                                           \
    __shared__ __align__(16) u16 As[2][128 * 64];                                 \
    __shared__ __align__(16) u16 Bs[2][128 * 64];                                 \
    const int tid  = threadIdx.x;                                                 \
    const int wave = tid >> 6;                                                    \
    const int lane = tid & 63;                                                    \
    const int l32  = lane & 31;                                                   \
    const int hl   = lane >> 5;                                                   \
    const int m0 = blockIdx.x * 128;                                              \
    const int n0 = blockIdx.y * 128;                                              \
    const int wm = (wave & 1) * 64;                                               \
    const int wn = (wave >> 1) * 64;                                              \
    f32x16 acc[2][2];                                                             \
    _Pragma("unroll")                                                             \
    for (int i = 0; i < 2; i++)                                                   \
        _Pragma("unroll")                                                         \
        for (int j = 0; j < 2; j++)                                               \
            _Pragma("unroll")                                                     \
            for (int e = 0; e < 16; e++) acc[i][j][e] = 0.f;                      \
    const int srow8 = lane >> 3;                                                  \
    const int scol  = ((lane & 7) ^ srow8) * 8;                                   \
    const u16* gA = Aptr + (size_t)(m0 + wave * 8 + srow8) * Kdim + scol;         \
    const u16* gB = Bptr + (size_t)(n0 + wave * 8 + srow8) * Kdim + scol;         \
    _Pragma("unroll")                                                             \
    for (int rnd = 0; rnd < 4; rnd++) {                                           \
        gl_lds(gA + (size_t)rnd * 32 * Kdim, &As[0][wave * 512 + rnd * 2048]);    \
        gl_lds(gB + (size_t)rnd * 32 * Kdim, &Bs[0][wave * 512 + rnd * 2048]);    \
    }                                                                             \
    const int NT = Kdim / 64;                                                     \
    for (int t = 0; t < NT; t++) {                                                \
        __syncthreads();  /* buf[t&1] ready; all waves done reading buf[(t-1)&1] */\
        if (t + 1 < NT) {                                                         \
            u16* dA = &As[(t + 1) & 1][wave * 512];                               \
            u16* dB = &Bs[(t + 1) & 1][wave * 512];                               \
            _Pragma("unroll")                                                     \
            for (int rnd = 0; rnd < 4; rnd++) {                                   \
                gl_lds(gA + (size_t)rnd * 32 * Kdim + (t + 1) * 64, dA + rnd * 2048); \
                gl_lds(gB + (size_t)rnd * 32 * Kdim + (t + 1) * 64, dB + rnd * 2048); \
            }                                                                     \
        }                                                                         \
        const u16* curA = As[t & 1];                                              \
        const u16* curB = Bs[t & 1];                                              \
        _Pragma("unroll")                                                         \
        for (int ks = 0; ks < 4; ks++) {                                          \
            bf16x8 af[2], bfv[2];                                                 \
            _Pragma("unroll")                                                     \
            for (int mi = 0; mi < 2; mi++) {                                      \
                const int row = wm + mi * 32 + l32;                               \
                const int c = (ks * 2 + hl) ^ (row & 7);                          \
                af[mi] = ld_frag(&curA[row * 64 + c * 8]);                        \
            }                                                                     \
            _Pragma("unroll")                                                     \
            for (int nj = 0; nj < 2; nj++) {                                      \
                const int row = wn + nj * 32 + l32;                               \
                const int c = (ks * 2 + hl) ^ (row & 7);                          \
                bfv[nj] = ld_frag(&curB[row * 64 + c * 8]);                       \
            }                                                                     \
            __builtin_amdgcn_s_setprio(1);                                        \
            _Pragma("unroll")                                                     \
            for (int mi = 0; mi < 2; mi++)                                        \
                _Pragma("unroll")                                                 \
                for (int nj = 0; nj < 2; nj++)                                    \
                    acc[mi][nj] = __builtin_amdgcn_mfma_f32_32x32x16_bf16(        \
                        af[mi], bfv[nj], acc[mi][nj], 0, 0, 0);                   \
            __builtin_amdgcn_s_setprio(0);                                        \
        }                                                                         \
    }

// qkv: Q (scaled) and K -> Cb[tok][2048]; V -> Cv transposed [bh][d][tok]
// C/D 32x32 mapping: tok = m0+wm+mi*32+(r&3)+8*(r>>2)+4*hl, gn = n0+wn+nj*32+l32
__global__ __launch_bounds__(256, 2)
void gemm_qkv(const u16* __restrict__ A, const u16* __restrict__ Bw,
              u16* __restrict__ Cb, u16* __restrict__ Cv)
{
    GEMM_PREAMBLE(A, Bw, 1024)

    #pragma unroll
    for (int nj = 0; nj < 2; nj++) {
        const int gn = n0 + wn + nj * 32 + l32;
        if (gn < 2048) {
            const float qs = (gn < 1024) ? ATT_SCALE : 1.0f;
            #pragma unroll
            for (int mi = 0; mi < 2; mi++) {
                #pragma unroll
                for (int r = 0; r < 16; r++) {
                    const int tok = m0 + wm + mi * 32 + (r & 3) + 8 * (r >> 2) + 4 * hl;
                    Cb[(size_t)tok * 2048 + gn] = f2bf(acc[mi][nj][r] * qs);
                }
            }
        } else {
            const int hh = (gn >> 7) & 7, dd = gn & 127;
            #pragma unroll
            for (int mi = 0; mi < 2; mi++) {
                #pragma unroll
                for (int r = 0; r < 16; r++) {
                    const int tok = m0 + wm + mi * 32 + (r & 3) + 8 * (r >> 2) + 4 * hl;
                    Cv[((size_t)((tok >> 11) * 8 + hh) * 128 + dd) * 2048 + (tok & 2047)] =
                        f2bf(acc[mi][nj][r]);
                }
            }
        }
    }
}

// C-sized matmuls: EPI 1 +bias+res f32; EPI 2 +bias ELU bf16; EPI 3 +bias ELU BN +res f32
template <int EPI>
__global__ __launch_bounds__(256, 2)
void gemm_c(const u16* __restrict__ A, const u16* __restrict__ Bw,
            const float* __restrict__ bias, const float* __restrict__ res,
            float* __restrict__ Cf, u16* __restrict__ Cb,
            const float* __restrict__ bng, const float* __restrict__ bnb,
            const float* __restrict__ bnm, const float* __restrict__ bnv)
{
    const int N = 1024;
    GEMM_PREAMBLE(A, Bw, 1024)

    #pragma unroll
    for (int nj = 0; nj < 2; nj++) {
        const int gn = n0 + wn + nj * 32 + l32;
        float bs = bias[gn], sc = 0.f, sh = 0.f;
        if constexpr (EPI == 3) {
            const float iv = rsqrtf(bnv[gn] + LN_EPS);
            sc = bng[gn] * iv;
            sh = bnb[gn] - bnm[gn] * sc;
        }
        #pragma unroll
        for (int mi = 0; mi < 2; mi++) {
            #pragma unroll
            for (int r = 0; r < 16; r++) {
                const int gm = m0 + wm + mi * 32 + (r & 3) + 8 * (r >> 2) + 4 * hl;
                const size_t idx = (size_t)gm * N + gn;
                const float v = acc[mi][nj][r];
                if constexpr (EPI == 1) {
                    Cf[idx] = res[idx] + v + bs;
                } else if constexpr (EPI == 2) {
                    float t = v + bs;
                    t = t > 0.f ? t : (__expf(t) - 1.f);
                    Cb[idx] = f2bf(t);
                } else {
                    float t = v + bs;
                    t = t > 0.f ? t : (__expf(t) - 1.f);
                    t = t * sc + sh;
                    Cf[idx] = res[idx] + t;
                }
            }
        }
    }
}

// ---------------------------------------------------------------- flash attention (R8 version: proven 84.3us)
// grid 512 (XCD-swizzled), 256 thr = 4 waves; 128 q/block; K-tile 64; D=128; K+V dbuf in LDS; 2 blocks/CU
// T5 setprio around MFMA; P^T half-swap via v_permlane32_swap (VALU pipe). Lane closed (R3/R5/R9/R10).
__global__ __launch_bounds__(256, 2)
void attn_kernel(const u16* __restrict__ qk, const u16* __restrict__ vT, u16* __restrict__ o)
{
    __shared__ __align__(16) u16 smem[32768];   // 64KB: buf0 [0,16384) buf1 [16384,32768)

    const int tid  = threadIdx.x;
    const int wave = tid >> 6;
    const int lane = tid & 63;
    const int l32  = lane & 31;
    const int hl   = lane >> 5;
    const int id   = blockIdx.x;
    const int bh   = ((id >> 7) << 3) | (id & 7);   // same-bh blocks cluster per XCD
    const int qt   = (id >> 3) & 15;
    const int b    = bh >> 3, h = bh & 7;
    const size_t tok0 = (size_t)b * 2048;

    const u16* qptr = qk + h * 128;
    const u16* kptr = qk + 1024 + h * 128;
    const u16* vptr = vT + (size_t)bh * 128 * 2048;

    // ---- stage Q tile [128 q][128 d] into buf1 region, xor-swizzled rows
    #pragma unroll
    for (int qq = 0; qq < 8; qq++) {
        const int s = qq * 256 + tid;
        const int r = s >> 4;
        const int cg = (s & 15) ^ (r & 7);
        const u16* g = qptr + (tok0 + qt * 128 + r) * 2048 + cg * 8;
        const int sb = 16384 + (qq * 256 + (tid & 192)) * 8;
        gl_lds(g, smem + sb);
    }
    __syncthreads();

    // ---- Q B-fragments (B[k=d][n=q]): n = l32, k = 16*ks + 8*hl + j
    bf16x8 qf[8];
    {
        const int row = wave * 32 + l32;
        #pragma unroll
        for (int ks = 0; ks < 8; ks++) {
            const int c = (ks * 2 + hl) ^ (row & 7);
            qf[ks] = ld_frag(smem + 16384 + row * 128 + c * 8);
        }
    }

    f32x16 oacc[4];
    #pragma unroll
    for (int i = 0; i < 4; i++)
        #pragma unroll
        for (int e = 0; e < 16; e++) oacc[i][e] = 0.f;
    float l_acc = 0.f;

    // ---- prefetch kt=0 into buf0
    {
        #pragma unroll
        for (int qq = 0; qq < 4; qq++) {
            const int s = qq * 256 + tid;
            const int rk = s >> 4, ck = (s & 15) ^ (rk & 7);
            gl_lds(kptr + (tok0 + rk) * 2048 + ck * 8,
                   smem + (qq * 256 + (tid & 192)) * 8);
            const int rv = s >> 3, cv = (s & 7) ^ (rv & 7);
            gl_lds(vptr + (size_t)rv * 2048 + cv * 8,
                   smem + 8192 + (qq * 256 + (tid & 192)) * 8);
        }
    }

    for (int kt = 0; kt < 32; kt++) {
        __syncthreads();

        if (kt + 1 < 32) {
            u16* nb = smem + ((kt + 1) & 1) * 16384;
            #pragma unroll
            for (int qq = 0; qq < 4; qq++) {
                const int s = qq * 256 + tid;
                const int rk = s >> 4, ck = (s & 15) ^ (rk & 7);
                gl_lds(kptr + (tok0 + (kt + 1) * 64 + rk) * 2048 + ck * 8,
                       nb + (qq * 256 + (tid & 192)) * 8);
                const int rv = s >> 3, cv = (s & 7) ^ (rv & 7);
                gl_lds(vptr + (size_t)rv * 2048 + (kt + 1) * 64 + cv * 8,
                       nb + 8192 + (qq * 256 + (tid & 192)) * 8);
            }
        }

        const u16* Ks = smem + (kt & 1) * 16384;
        const u16* Vs = Ks + 8192;

        // ---- S^T = K . Q^T
        f32x16 sacc[2];
        #pragma unroll
        for (int t = 0; t < 2; t++)
            #pragma unroll
            for (int e = 0; e < 16; e++) sacc[t][e] = 0.f;
        __builtin_amdgcn_s_setprio(1);
        #pragma unroll
        for (int ks = 0; ks < 8; ks++) {
            #pragma unroll
            for (int mt = 0; mt < 2; mt++) {
                const int row = mt * 32 + l32;
                const int c = (ks * 2 + hl) ^ (row & 7);
                const bf16x8 kf = ld_frag(Ks + row * 128 + c * 8);
                sacc[mt] = __builtin_amdgcn_mfma_f32_32x32x16_bf16(kf, qf[ks], sacc[mt], 0, 0, 0);
            }
        }
        __builtin_amdgcn_s_setprio(0);

        // ---- p = exp(s), l accumulate, pack bf16
        unsigned pk[2][8];
        #pragma unroll
        for (int t = 0; t < 2; t++) {
            #pragma unroll
            for (int r2 = 0; r2 < 8; r2++) {
                const float p0 = __expf(sacc[t][2 * r2]);
                const float p1 = __expf(sacc[t][2 * r2 + 1]);
                l_acc += p0 + p1;
                pk[t][r2] = pack_bf2(p0, p1);
            }
        }

        // ---- O^T += V^T . P^T : P^T B-frag via permlane32_swap (VALU pipe, no LDS)
        #pragma unroll
        for (int ks = 0; ks < 4; ks++) {
            const int t = ks >> 1;
            const int pb = (ks & 1) * 4;
            const u32x2 r02 = __builtin_amdgcn_permlane32_swap(pk[t][pb + 0], pk[t][pb + 2], false, false);
            const u32x2 r13 = __builtin_amdgcn_permlane32_swap(pk[t][pb + 1], pk[t][pb + 3], false, false);
            u32x4 pu;
            pu.x = r02.x; pu.y = r13.x; pu.z = r02.y; pu.w = r13.y;
            const bf16x8 pf = __builtin_bit_cast(bf16x8, pu);
            __builtin_amdgcn_s_setprio(1);
            #pragma unroll
            for (int dt = 0; dt < 4; dt++) {
                const int row = dt * 32 + l32;
                const int c = (ks * 2 + hl) ^ (row & 7);
                const bf16x8 vf = ld_frag(Vs + row * 64 + c * 8);
                oacc[dt] = __builtin_amdgcn_mfma_f32_32x32x16_bf16(vf, pf, oacc[dt], 0, 0, 0);
            }
            __builtin_amdgcn_s_setprio(0);
        }
    }

    // ---- epilogue: O^T/l -> bf16, transpose via LDS, coalesced store
    __syncthreads();
    u16* Ot = smem;   // [128 q][136]
    const float lt  = l_acc + __shfl_xor(l_acc, 32);
    const float inv = 1.0f / lt;
    const int qloc = wave * 32 + l32;
    #pragma unroll
    for (int dt = 0; dt < 4; dt++) {
        #pragma unroll
        for (int r2 = 0; r2 < 8; r2++) {
            const float v0 = oacc[dt][2 * r2] * inv;
            const float v1 = oacc[dt][2 * r2 + 1] * inv;
            const int dp = dt * 32 + 4 * hl + 2 * (r2 & 1) + 8 * (r2 >> 1);
            *(unsigned*)(Ot + qloc * 136 + dp) = pack_bf2(v0, v1);
        }
    }
    __syncthreads();
    const int qr = tid >> 1;
    const int hh = tid & 1;
    const u16* src = Ot + qr * 136 + hh * 64;
    u16* dst = o + (tok0 + qt * 128 + qr) * 1024 + h * 128 + hh * 64;
    #pragma unroll
    for (int c = 0; c < 8; c++)
        *(u32x4*)(dst + c * 8) = *(const u32x4*)(src + c * 8);
}

// ---------------------------------------------------------------- launch
extern "C" void kernel_launch(void* const* d_in, const int* in_sizes, int n_in,
                              void* d_out, int out_size, void* d_ws, size_t ws_size,
                              hipStream_t stream)
{
    const float* x      = (const float*)d_in[0];
    const float* ln1_g  = (const float*)d_in[1];
    const float* ln1_b  = (const float*)d_in[2];
    const float* w_qkv  = (const float*)d_in[3];
    const float* w_proj = (const float*)d_in[4];
    const float* b_proj = (const float*)d_in[5];
    const float* ln2_g  = (const float*)d_in[6];
    const float* ln2_b  = (const float*)d_in[7];
    const float* w1     = (const float*)d_in[8];
    const float* b1     = (const float*)d_in[9];
    const float* w2     = (const float*)d_in[10];
    const float* b2     = (const float*)d_in[11];
    const float* bn_g   = (const float*)d_in[12];
    const float* bn_b   = (const float*)d_in[13];
    const float* bn_m   = (const float*)d_in[14];
    const float* bn_v   = (const float*)d_in[15];
    float* out = (float*)d_out;

    // workspace carve-up (u16 units), ~124 MB total
    u16* wq   = (u16*)d_ws;                          // 3072*1024
    u16* wp   = wq  + (size_t)3072 * 1024;           // 1024*1024
    u16* w1b  = wp  + (size_t)1024 * 1024;
    u16* w2b  = w1b + (size_t)1024 * 1024;
    u16* hbuf = w2b + (size_t)1024 * 1024;           // 8192*1024 (LN out, reused)
    u16* qkb  = hbuf + (size_t)8192 * 1024;          // 8192*2048 (Q scaled | K)
    u16* vTb  = qkb + (size_t)8192 * 2048;           // 32*128*2048 (V transposed)
    u16* obuf = vTb + (size_t)8192 * 1024;           // 8192*1024 (attn out; reused mlp1 out)
    float* x1 = (float*)(obuf + (size_t)8192 * 1024); // 8192*1024 f32

    cvt_ln<<<14336, 256, 0, stream>>>(x, ln1_g, ln1_b, hbuf, w_qkv, w_proj, w1, w2, wq);

    gemm_qkv<<<dim3(64, 24), 256, 0, stream>>>(hbuf, wq, qkb, vTb);

    attn_kernel<<<512, 256, 0, stream>>>(qkb, vTb, obuf);

    gemm_c<1><<<dim3(64, 8), 256, 0, stream>>>(obuf, wp,
        b_proj, x, x1, nullptr, nullptr, nullptr, nullptr, nullptr);

    ln_kernel<<<8192, 256, 0, stream>>>(x1, ln2_g, ln2_b, hbuf);

    gemm_c<2><<<dim3(64, 8), 256, 0, stream>>>(hbuf, w1b,
        b1, nullptr, nullptr, obuf, nullptr, nullptr, nullptr, nullptr);

    gemm_c<3><<<dim3(64, 8), 256, 0, stream>>>(obuf, w2b,
        b2, x1, out, nullptr, bn_g, bn_b, bn_m, bn_v);
}

// Round 14
// 348.669 us; speedup vs baseline: 1.0972x; 1.0521x over previous
//
#include <hip/hip_runtime.h>
#include <hip/hip_bf16.h>

using u16 = unsigned short;
typedef __attribute__((ext_vector_type(8))) __bf16 bf16x8;
typedef __attribute__((ext_vector_type(4))) float f32x4;
typedef __attribute__((ext_vector_type(16))) float f32x16;
typedef __attribute__((ext_vector_type(4))) unsigned int u32x4;
typedef __attribute__((ext_vector_type(2))) unsigned int u32x2;

#define LN_EPS 1e-5f
#define ATT_SCALE 0.08838834764831845f   // 1/sqrt(128)

__device__ __forceinline__ u16 f2bf(float f) {
    unsigned int u = __builtin_bit_cast(unsigned int, f);
    u += 0x7FFFu + ((u >> 16) & 1u);     // RNE
    return (u16)(u >> 16);
}

__device__ __forceinline__ bf16x8 ld_frag(const u16* p) {
    return __builtin_bit_cast(bf16x8, *(const u32x4*)p);
}

// pack two f32 -> two bf16 (truncate) in one v_perm
__device__ __forceinline__ unsigned pack_bf2(float lo, float hi) {
    return __builtin_amdgcn_perm(__builtin_bit_cast(unsigned, hi),
                                 __builtin_bit_cast(unsigned, lo), 0x07060302u);
}

__device__ __forceinline__ void gl_lds(const u16* g, u16* l) {
    __builtin_amdgcn_global_load_lds((const __attribute__((address_space(1))) void*)g,
                                     (__attribute__((address_space(3))) void*)l, 16, 0, 0);
}

// ---------------------------------------------------------------- fused: weight-convert + LN1
__global__ __launch_bounds__(256)
void cvt_ln(const float* __restrict__ x, const float* __restrict__ g,
            const float* __restrict__ b, u16* __restrict__ hout,
            const float* __restrict__ w_qkv, const float* __restrict__ w_proj,
            const float* __restrict__ w1, const float* __restrict__ w2,
            u16* __restrict__ wout)
{
    const int t = threadIdx.x;
    if (blockIdx.x < 8192) {
        const int row = blockIdx.x;
        const float4 v = ((const float4*)(x + (size_t)row * 1024))[t];
        float s  = v.x + v.y + v.z + v.w;
        float ss = v.x * v.x + v.y * v.y + v.z * v.z + v.w * v.w;
        #pragma unroll
        for (int d = 32; d > 0; d >>= 1) { s += __shfl_down(s, d); ss += __shfl_down(ss, d); }
        __shared__ float red[8];
        const int wave = t >> 6, lane = t & 63;
        if (lane == 0) { red[wave] = s; red[4 + wave] = ss; }
        __syncthreads();
        const float S  = red[0] + red[1] + red[2] + red[3];
        const float SS = red[4] + red[5] + red[6] + red[7];
        const float mu = S * (1.f / 1024.f);
        const float rstd = rsqrtf(SS * (1.f / 1024.f) - mu * mu + LN_EPS);
        const float4 gv = ((const float4*)g)[t];
        const float4 bv = ((const float4*)b)[t];
        ushort4 ov;
        ov.x = f2bf((v.x - mu) * rstd * gv.x + bv.x);
        ov.y = f2bf((v.y - mu) * rstd * gv.y + bv.y);
        ov.z = f2bf((v.z - mu) * rstd * gv.z + bv.z);
        ov.w = f2bf((v.w - mu) * rstd * gv.w + bv.w);
        ((ushort4*)(hout + (size_t)row * 1024))[t] = ov;
    } else {
        const int i = (blockIdx.x - 8192) * 256 + t;
        const int n_qkv = 3072 * 1024 / 4, n_c = 1024 * 1024 / 4;
        const float* src;
        int j = i;
        if (j < n_qkv) { src = w_qkv; }
        else if ((j -= n_qkv) < n_c) { src = w_proj; }
        else if ((j -= n_c) < n_c)   { src = w1; }
        else { j -= n_c; src = w2; }
        const float4 v = ((const float4*)src)[j];
        ushort4 o;
        o.x = f2bf(v.x); o.y = f2bf(v.y); o.z = f2bf(v.z); o.w = f2bf(v.w);
        ((ushort4*)wout)[i] = o;
    }
}

// ---------------------------------------------------------------- layernorm
__global__ __launch_bounds__(256)
void ln_kernel(const float* __restrict__ x, const float* __restrict__ g,
               const float* __restrict__ b, u16* __restrict__ out)
{
    const int row = blockIdx.x;
    const int t = threadIdx.x;
    const float4 v = ((const float4*)(x + (size_t)row * 1024))[t];
    float s  = v.x + v.y + v.z + v.w;
    float ss = v.x * v.x + v.y * v.y + v.z * v.z + v.w * v.w;
    #pragma unroll
    for (int d = 32; d > 0; d >>= 1) { s += __shfl_down(s, d); ss += __shfl_down(ss, d); }
    __shared__ float red[8];
    const int wave = t >> 6, lane = t & 63;
    if (lane == 0) { red[wave] = s; red[4 + wave] = ss; }
    __syncthreads();
    const float S  = red[0] + red[1] + red[2] + red[3];
    const float SS = red[4] + red[5] + red[6] + red[7];
    const float mu = S * (1.f / 1024.f);
    const float rstd = rsqrtf(SS * (1.f / 1024.f) - mu * mu + LN_EPS);
    const float4 gv = ((const float4*)g)[t];
    const float4 bv = ((const float4*)b)[t];
    ushort4 ov;
    ov.x = f2bf((v.x - mu) * rstd * gv.x + bv.x);
    ov.y = f2bf((v.y - mu) * rstd * gv.y + bv.y);
    ov.z = f2bf((v.z - mu) * rstd * gv.z + bv.z);
    ov.w = f2bf((v.w - mu) * rstd * gv.w + bv.w);
    ((ushort4*)(out + (size_t)row * 1024))[t] = ov;
}

// ---------------------------------------------------------------- 128x128 GEMM, BK=64, double-buffered
// (2-phase dbuf: STAGE(t+1) before compute(t); single barrier per K-step.) LDS 64KB -> 2 blocks/CU.
// Plain blockIdx mapping (default x-major round-robin partitions A across XCDs; R7: swizzle regresses).
// 16x16x32 MFMA shape (R13: 32x32x16 regressed -- fewer independent accs exposes dep chains at ~40% util).
#define GEMM_PREAMBLE(Aptr, Bptr, Kdim)                                           \
    __shared__ __align__(16) u16 As[2][128 * 64];                                 \
    __shared__ __align__(16) u16 Bs[2][128 * 64];                                 \
    const int tid  = threadIdx.x;                                                 \
    const int wave = tid >> 6;                                                    \
    const int lane = tid & 63;                                                    \
    const int quad = lane >> 4;                                                   \
    const int l16  = lane & 15;                                                   \
    const int m0 = blockIdx.x * 128;                                              \
    const int n0 = blockIdx.y * 128;                                              \
    const int wm = (wave & 1) * 64;                                               \
    const int wn = (wave >> 1) * 64;                                              \
    f32x4 acc[4][4];                                                              \
    _Pragma("unroll")                                                             \
    for (int i = 0; i < 4; i++)                                                   \
        _Pragma("unroll")                                                         \
        for (int j = 0; j < 4; j++)                                               \
            acc[i][j] = f32x4{0.f, 0.f, 0.f, 0.f};                                \
    const int srow8 = lane >> 3;                                                  \
    const int scol  = ((lane & 7) ^ srow8) * 8;                                   \
    const u16* gA = Aptr + (size_t)(m0 + wave * 8 + srow8) * Kdim + scol;         \
    const u16* gB = Bptr + (size_t)(n0 + wave * 8 + srow8) * Kdim + scol;         \
    _Pragma("unroll")                                                             \
    for (int rnd = 0; rnd < 4; rnd++) {                                           \
        gl_lds(gA + (size_t)rnd * 32 * Kdim, &As[0][wave * 512 + rnd * 2048]);    \
        gl_lds(gB + (size_t)rnd * 32 * Kdim, &Bs[0][wave * 512 + rnd * 2048]);    \
    }                                                                             \
    const int NT = Kdim / 64;                                                     \
    for (int t = 0; t < NT; t++) {                                                \
        __syncthreads();  /* buf[t&1] ready; all waves done reading buf[(t-1)&1] */\
        if (t + 1 < NT) {                                                         \
            u16* dA = &As[(t + 1) & 1][wave * 512];                               \
            u16* dB = &Bs[(t + 1) & 1][wave * 512];                               \
            _Pragma("unroll")                                                     \
            for (int rnd = 0; rnd < 4; rnd++) {                                   \
                gl_lds(gA + (size_t)rnd * 32 * Kdim + (t + 1) * 64, dA + rnd * 2048); \
                gl_lds(gB + (size_t)rnd * 32 * Kdim + (t + 1) * 64, dB + rnd * 2048); \
            }                                                                     \
        }                                                                         \
        const u16* curA = As[t & 1];                                              \
        const u16* curB = Bs[t & 1];                                              \
        _Pragma("unroll")                                                         \
        for (int kk = 0; kk < 2; kk++) {                                          \
            bf16x8 af[4], bfv[4];                                                 \
            _Pragma("unroll")                                                     \
            for (int i = 0; i < 4; i++) {                                         \
                const int row = wm + i * 16 + l16;                                \
                const int c = (kk * 4 + quad) ^ (row & 7);                        \
                af[i] = ld_frag(&curA[row * 64 + c * 8]);                         \
            }                                                                     \
            _Pragma("unroll")                                                     \
            for (int j = 0; j < 4; j++) {                                         \
                const int row = wn + j * 16 + l16;                                \
                const int c = (kk * 4 + quad) ^ (row & 7);                        \
                bfv[j] = ld_frag(&curB[row * 64 + c * 8]);                        \
            }                                                                     \
            __builtin_amdgcn_s_setprio(1);                                        \
            _Pragma("unroll")                                                     \
            for (int i = 0; i < 4; i++)                                           \
                _Pragma("unroll")                                                 \
                for (int j = 0; j < 4; j++)                                       \
                    acc[i][j] = __builtin_amdgcn_mfma_f32_16x16x32_bf16(          \
                        af[i], bfv[j], acc[i][j], 0, 0, 0);                       \
            __builtin_amdgcn_s_setprio(0);                                        \
        }                                                                         \
    }

// qkv: Q (scaled) and K -> Cb[tok][2048]; V -> Cv transposed [bh][d][tok]  (R2 scatter epilogue)
__global__ __launch_bounds__(256, 2)
void gemm_qkv(const u16* __restrict__ A, const u16* __restrict__ Bw,
              u16* __restrict__ Cb, u16* __restrict__ Cv)
{
    GEMM_PREAMBLE(A, Bw, 1024)

    #pragma unroll
    for (int j = 0; j < 4; j++) {
        const int gn = n0 + wn + j * 16 + l16;
        if (gn < 2048) {
            const float qs = (gn < 1024) ? ATT_SCALE : 1.0f;
            #pragma unroll
            for (int i = 0; i < 4; i++) {
                const int gm0 = m0 + wm + i * 16 + quad * 4;
                #pragma unroll
                for (int r = 0; r < 4; r++)
                    Cb[(size_t)(gm0 + r) * 2048 + gn] = f2bf(acc[i][j][r] * qs);
            }
        } else {
            const int hh = (gn >> 7) & 7, dd = gn & 127;
            #pragma unroll
            for (int i = 0; i < 4; i++) {
                const int gm0 = m0 + wm + i * 16 + quad * 4;
                #pragma unroll
                for (int r = 0; r < 4; r++) {
                    const int tok = gm0 + r;
                    Cv[((size_t)((tok >> 11) * 8 + hh) * 128 + dd) * 2048 + (tok & 2047)] =
                        f2bf(acc[i][j][r]);
                }
            }
        }
    }
}

// C-sized matmuls: EPI 1 +bias+res f32; EPI 2 +bias ELU bf16; EPI 3 +bias ELU BN +res f32
template <int EPI>
__global__ __launch_bounds__(256, 2)
void gemm_c(const u16* __restrict__ A, const u16* __restrict__ Bw,
            const float* __restrict__ bias, const float* __restrict__ res,
            float* __restrict__ Cf, u16* __restrict__ Cb,
            const float* __restrict__ bng, const float* __restrict__ bnb,
            const float* __restrict__ bnm, const float* __restrict__ bnv)
{
    const int N = 1024;
    GEMM_PREAMBLE(A, Bw, 1024)

    #pragma unroll
    for (int j = 0; j < 4; j++) {
        const int gn = n0 + wn + j * 16 + l16;
        float bs = bias[gn], sc = 0.f, sh = 0.f;
        if constexpr (EPI == 3) {
            const float iv = rsqrtf(bnv[gn] + LN_EPS);
            sc = bng[gn] * iv;
            sh = bnb[gn] - bnm[gn] * sc;
        }
        #pragma unroll
        for (int i = 0; i < 4; i++) {
            const int gm0 = m0 + wm + i * 16 + quad * 4;
            #pragma unroll
            for (int r = 0; r < 4; r++) {
                const size_t idx = (size_t)(gm0 + r) * N + gn;
                const float v = acc[i][j][r];
                if constexpr (EPI == 1) {
                    Cf[idx] = res[idx] + v + bs;
                } else if constexpr (EPI == 2) {
                    float t = v + bs;
                    t = t > 0.f ? t : (__expf(t) - 1.f);
                    Cb[idx] = f2bf(t);
                } else {
                    float t = v + bs;
                    t = t > 0.f ? t : (__expf(t) - 1.f);
                    t = t * sc + sh;
                    Cf[idx] = res[idx] + t;
                }
            }
        }
    }
}

// ---------------------------------------------------------------- flash attention (R8 version: proven 84.3us)
// grid 512 (XCD-swizzled), 256 thr = 4 waves; 128 q/block; K-tile 64; D=128; K+V dbuf in LDS; 2 blocks/CU
// T5 setprio around MFMA; P^T half-swap via v_permlane32_swap (VALU pipe). Lane closed (R3/R5/R9/R10).
__global__ __launch_bounds__(256, 2)
void attn_kernel(const u16* __restrict__ qk, const u16* __restrict__ vT, u16* __restrict__ o)
{
    __shared__ __align__(16) u16 smem[32768];   // 64KB: buf0 [0,16384) buf1 [16384,32768)

    const int tid  = threadIdx.x;
    const int wave = tid >> 6;
    const int lane = tid & 63;
    const int l32  = lane & 31;
    const int hl   = lane >> 5;
    const int id   = blockIdx.x;
    const int bh   = ((id >> 7) << 3) | (id & 7);   // same-bh blocks cluster per XCD
    const int qt   = (id >> 3) & 15;
    const int b    = bh >> 3, h = bh & 7;
    const size_t tok0 = (size_t)b * 2048;

    const u16* qptr = qk + h * 128;
    const u16* kptr = qk + 1024 + h * 128;
    const u16* vptr = vT + (size_t)bh * 128 * 2048;

    // ---- stage Q tile [128 q][128 d] into buf1 region, xor-swizzled rows
    #pragma unroll
    for (int qq = 0; qq < 8; qq++) {
        const int s = qq * 256 + tid;
        const int r = s >> 4;
        const int cg = (s & 15) ^ (r & 7);
        const u16* g = qptr + (tok0 + qt * 128 + r) * 2048 + cg * 8;
        const int sb = 16384 + (qq * 256 + (tid & 192)) * 8;
        gl_lds(g, smem + sb);
    }
    __syncthreads();

    // ---- Q B-fragments (B[k=d][n=q]): n = l32, k = 16*ks + 8*hl + j
    bf16x8 qf[8];
    {
        const int row = wave * 32 + l32;
        #pragma unroll
        for (int ks = 0; ks < 8; ks++) {
            const int c = (ks * 2 + hl) ^ (row & 7);
            qf[ks] = ld_frag(smem + 16384 + row * 128 + c * 8);
        }
    }

    f32x16 oacc[4];
    #pragma unroll
    for (int i = 0; i < 4; i++)
        #pragma unroll
        for (int e = 0; e < 16; e++) oacc[i][e] = 0.f;
    float l_acc = 0.f;

    // ---- prefetch kt=0 into buf0
    {
        #pragma unroll
        for (int qq = 0; qq < 4; qq++) {
            const int s = qq * 256 + tid;
            const int rk = s >> 4, ck = (s & 15) ^ (rk & 7);
            gl_lds(kptr + (tok0 + rk) * 2048 + ck * 8,
                   smem + (qq * 256 + (tid & 192)) * 8);
            const int rv = s >> 3, cv = (s & 7) ^ (rv & 7);
            gl_lds(vptr + (size_t)rv * 2048 + cv * 8,
                   smem + 8192 + (qq * 256 + (tid & 192)) * 8);
        }
    }

    for (int kt = 0; kt < 32; kt++) {
        __syncthreads();

        if (kt + 1 < 32) {
            u16* nb = smem + ((kt + 1) & 1) * 16384;
            #pragma unroll
            for (int qq = 0; qq < 4; qq++) {
                const int s = qq * 256 + tid;
                const int rk = s >> 4, ck = (s & 15) ^ (rk & 7);
                gl_lds(kptr + (tok0 + (kt + 1) * 64 + rk) * 2048 + ck * 8,
                       nb + (qq * 256 + (tid & 192)) * 8);
                const int rv = s >> 3, cv = (s & 7) ^ (rv & 7);
                gl_lds(vptr + (size_t)rv * 2048 + (kt + 1) * 64 + cv * 8,
                       nb + 8192 + (qq * 256 + (tid & 192)) * 8);
            }
        }

        const u16* Ks = smem + (kt & 1) * 16384;
        const u16* Vs = Ks + 8192;

        // ---- S^T = K . Q^T
        f32x16 sacc[2];
        #pragma unroll
        for (int t = 0; t < 2; t++)
            #pragma unroll
            for (int e = 0; e < 16; e++) sacc[t][e] = 0.f;
        __builtin_amdgcn_s_setprio(1);
        #pragma unroll
        for (int ks = 0; ks < 8; ks++) {
            #pragma unroll
            for (int mt = 0; mt < 2; mt++) {
                const int row = mt * 32 + l32;
                const int c = (ks * 2 + hl) ^ (row & 7);
                const bf16x8 kf = ld_frag(Ks + row * 128 + c * 8);
                sacc[mt] = __builtin_amdgcn_mfma_f32_32x32x16_bf16(kf, qf[ks], sacc[mt], 0, 0, 0);
            }
        }
        __builtin_amdgcn_s_setprio(0);

        // ---- p = exp(s), l accumulate, pack bf16
        unsigned pk[2][8];
        #pragma unroll
        for (int t = 0; t < 2; t++) {
            #pragma unroll
            for (int r2 = 0; r2 < 8; r2++) {
                const float p0 = __expf(sacc[t][2 * r2]);
                const float p1 = __expf(sacc[t][2 * r2 + 1]);
                l_acc += p0 + p1;
                pk[t][r2] = pack_bf2(p0, p1);
            }
        }

        // ---- O^T += V^T . P^T : P^T B-frag via permlane32_swap (VALU pipe, no LDS)
        #pragma unroll
        for (int ks = 0; ks < 4; ks++) {
            const int t = ks >> 1;
            const int pb = (ks & 1) * 4;
            const u32x2 r02 = __builtin_amdgcn_permlane32_swap(pk[t][pb + 0], pk[t][pb + 2], false, false);
            const u32x2 r13 = __builtin_amdgcn_permlane32_swap(pk[t][pb + 1], pk[t][pb + 3], false, false);
            u32x4 pu;
            pu.x = r02.x; pu.y = r13.x; pu.z = r02.y; pu.w = r13.y;
            const bf16x8 pf = __builtin_bit_cast(bf16x8, pu);
            __builtin_amdgcn_s_setprio(1);
            #pragma unroll
            for (int dt = 0; dt < 4; dt++) {
                const int row = dt * 32 + l32;
                const int c = (ks * 2 + hl) ^ (row & 7);
                const bf16x8 vf = ld_frag(Vs + row * 64 + c * 8);
                oacc[dt] = __builtin_amdgcn_mfma_f32_32x32x16_bf16(vf, pf, oacc[dt], 0, 0, 0);
            }
            __builtin_amdgcn_s_setprio(0);
        }
    }

    // ---- epilogue: O^T/l -> bf16, transpose via LDS, coalesced store
    __syncthreads();
    u16* Ot = smem;   // [128 q][136]
    const float lt  = l_acc + __shfl_xor(l_acc, 32);
    const float inv = 1.0f / lt;
    const int qloc = wave * 32 + l32;
    #pragma unroll
    for (int dt = 0; dt < 4; dt++) {
        #pragma unroll
        for (int r2 = 0; r2 < 8; r2++) {
            const float v0 = oacc[dt][2 * r2] * inv;
            const float v1 = oacc[dt][2 * r2 + 1] * inv;
            const int dp = dt * 32 + 4 * hl + 2 * (r2 & 1) + 8 * (r2 >> 1);
            *(unsigned*)(Ot + qloc * 136 + dp) = pack_bf2(v0, v1);
        }
    }
    __syncthreads();
    const int qr = tid >> 1;
    const int hh = tid & 1;
    const u16* src = Ot + qr * 136 + hh * 64;
    u16* dst = o + (tok0 + qt * 128 + qr) * 1024 + h * 128 + hh * 64;
    #pragma unroll
    for (int c = 0; c < 8; c++)
        *(u32x4*)(dst + c * 8) = *(const u32x4*)(src + c * 8);
}

// ---------------------------------------------------------------- launch
extern "C" void kernel_launch(void* const* d_in, const int* in_sizes, int n_in,
                              void* d_out, int out_size, void* d_ws, size_t ws_size,
                              hipStream_t stream)
{
    const float* x      = (const float*)d_in[0];
    const float* ln1_g  = (const float*)d_in[1];
    const float* ln1_b  = (const float*)d_in[2];
    const float* w_qkv  = (const float*)d_in[3];
    const float* w_proj = (const float*)d_in[4];
    const float* b_proj = (const float*)d_in[5];
    const float* ln2_g  = (const float*)d_in[6];
    const float* ln2_b  = (const float*)d_in[7];
    const float* w1     = (const float*)d_in[8];
    const float* b1     = (const float*)d_in[9];
    const float* w2     = (const float*)d_in[10];
    const float* b2     = (const float*)d_in[11];
    const float* bn_g   = (const float*)d_in[12];
    const float* bn_b   = (const float*)d_in[13];
    const float* bn_m   = (const float*)d_in[14];
    const float* bn_v   = (const float*)d_in[15];
    float* out = (float*)d_out;

    // workspace carve-up (u16 units), ~124 MB total
    u16* wq   = (u16*)d_ws;                          // 3072*1024
    u16* wp   = wq  + (size_t)3072 * 1024;           // 1024*1024
    u16* w1b  = wp  + (size_t)1024 * 1024;
    u16* w2b  = w1b + (size_t)1024 * 1024;
    u16* hbuf = w2b + (size_t)1024 * 1024;           // 8192*1024 (LN out, reused)
    u16* qkb  = hbuf + (size_t)8192 * 1024;          // 8192*2048 (Q scaled | K)
    u16* vTb  = qkb + (size_t)8192 * 2048;           // 32*128*2048 (V transposed)
    u16* obuf = vTb + (size_t)8192 * 1024;           // 8192*1024 (attn out; reused mlp1 out)
    float* x1 = (float*)(obuf + (size_t)8192 * 1024); // 8192*1024 f32

    cvt_ln<<<14336, 256, 0, stream>>>(x, ln1_g, ln1_b, hbuf, w_qkv, w_proj, w1, w2, wq);

    gemm_qkv<<<dim3(64, 24), 256, 0, stream>>>(hbuf, wq, qkb, vTb);

    attn_kernel<<<512, 256, 0, stream>>>(qkb, vTb, obuf);

    gemm_c<1><<<dim3(64, 8), 256, 0, stream>>>(obuf, wp,
        b_proj, x, x1, nullptr, nullptr, nullptr, nullptr, nullptr);

    ln_kernel<<<8192, 256, 0, stream>>>(x1, ln2_g, ln2_b, hbuf);

    gemm_c<2><<<dim3(64, 8), 256, 0, stream>>>(hbuf, w1b,
        b1, nullptr, nullptr, obuf, nullptr, nullptr, nullptr, nullptr);

    gemm_c<3><<<dim3(64, 8), 256, 0, stream>>>(obuf, w2b,
        b2, x1, out, nullptr, bn_g, bn_b, bn_m, bn_v);
}